// Round 10
// baseline (127.110 us; speedup 1.0000x reference)
//
#include <hip/hip_runtime.h>
#include <hip/hip_bf16.h>

#define GN    8192
#define FIN   256
#define FOUT  64
#define LOG2E 1.44269504f

typedef float  f32x4  __attribute__((ext_vector_type(4)));
typedef __bf16 bf16x8 __attribute__((ext_vector_type(8)));
typedef int    iv4    __attribute__((ext_vector_type(4)));

__device__ __forceinline__ unsigned short f2bf_rtne(float x) {
    unsigned int u = __float_as_uint(x);
    unsigned int r = (u + 0x7FFFu + ((u >> 16) & 1u)) >> 16;
    return (unsigned short)r;
}

// global -> LDS DMA, 16 B per lane. LDS dest must be wave-uniform; HW writes
// ldsbase + lane*16. Global src is per-lane.
__device__ __forceinline__ void gload_lds16(const void* g, void* l) {
    __builtin_amdgcn_global_load_lds(
        (const __attribute__((address_space(1))) void*)g,
        (__attribute__((address_space(3))) void*)l, 16, 0, 0);
}

// ---------------------------------------------------------------------------
// K1: Wh = h @ W (fp32), f_src/f_dst (log2e pre-scaled, clamped), and pack
// 32 Wh rows into bf16 MFMA B-fragment layout with the within-chunk
// permutation  k = gb*8 + e  <->  j = gb*4 + (e&3) + 16*(e>>2).  (unchanged)
// ---------------------------------------------------------------------------
__global__ __launch_bounds__(256) void k_wh(const float* __restrict__ h,
                                            const float* __restrict__ W,
                                            const float* __restrict__ a,
                                            float* __restrict__ fsrc,
                                            float* __restrict__ fdst,
                                            uint4* __restrict__ whfrag) {
    __shared__ float Wt[FOUT][FIN + 1];
    __shared__ float WhL[32][FOUT + 1];
    int t = threadIdx.x;
    int col = t & 63, kq4 = t >> 6;
#pragma unroll
    for (int rep = 0; rep < 16; ++rep) {
        int k0 = kq4 * 4 + rep * 16;
        float4 wv;
        wv.x = W[(k0 + 0) * FOUT + col];
        wv.y = W[(k0 + 1) * FOUT + col];
        wv.z = W[(k0 + 2) * FOUT + col];
        wv.w = W[(k0 + 3) * FOUT + col];
        *(float4*)&Wt[col][k0] = wv;
    }
    __syncthreads();
    int wave = t >> 6, lane = t & 63;
    float a1 = a[lane], a2 = a[FOUT + lane];
    int bid = blockIdx.x;
#pragma unroll
    for (int rr = 0; rr < 8; ++rr) {
        int il = wave * 8 + rr;
        int i  = bid * 32 + il;
        const float* hrow = h + (size_t)i * FIN;
        float acc = 0.f;
#pragma unroll 8
        for (int k0 = 0; k0 < FIN; k0 += 4) {
            float4 hv = *(const float4*)&hrow[k0];
            float4 wv = *(const float4*)&Wt[lane][k0];
            acc += hv.x * wv.x + hv.y * wv.y + hv.z * wv.z + hv.w * wv.w;
        }
        WhL[il][lane] = acc;
        float v1 = acc * a1, v2 = acc * a2;
#pragma unroll
        for (int off = 32; off > 0; off >>= 1) {
            v1 += __shfl_xor(v1, off);
            v2 += __shfl_xor(v2, off);
        }
        if (lane == 0) {
            fsrc[i] = fminf(v1, 30.f) * LOG2E;
            fdst[i] = fminf(v2, 30.f) * LOG2E;
        }
    }
    __syncthreads();
    int lane2 = t & 63, ct = t >> 6;
    int colc = ct * 16 + (lane2 & 15);
    int gb = lane2 >> 4;
    unsigned int pk[4];
#pragma unroll
    for (int p = 0; p < 4; ++p) {
        int jo = ((p >> 1) * 16) + gb * 4 + (p & 1) * 2;
        unsigned int lo = f2bf_rtne(WhL[jo    ][colc]);
        unsigned int hi = f2bf_rtne(WhL[jo + 1][colc]);
        pk[p] = lo | (hi << 16);
    }
    uint4 o; o.x = pk[0]; o.y = pk[1]; o.z = pk[2]; o.w = pk[3];
    whfrag[(size_t)(bid * 4 + ct) * 64 + lane2] = o;
}

// ---------------------------------------------------------------------------
// K2: single-pass GAT. Block = 32 rows x FULL j (no partials, no k_out).
// 8 waves: m = wv>>2 (row half, 16 rows), p = wv&3 (j parity: chunks c==p%4).
// Per phase (32 phases): 2 chunks/wave staged via global_load_lds into
// wave-private double-buffered LDS; b-fragments from global (L2-resident,
// issued BEFORE glds so in-order vmcnt retire never blocks them on HBM);
// __syncthreads per phase guarantees DMA completion. Epilogue reduces the
// 4 j-parities via LDS (aliased over the dead staging buffer), ELU, write.
// ---------------------------------------------------------------------------
__global__ __launch_bounds__(512, 1) void k_gat(const int* __restrict__ adj,
                                                const float* __restrict__ fsrc,
                                                const float* __restrict__ fdst,
                                                const uint4* __restrict__ whfrag,
                                                float* __restrict__ out) {
    __shared__ __align__(16) unsigned char smem[32768 + 65536 + 512];
    float* fsL  = (float*)smem;                   // 32 KB: fsrc staged
    int*   abuf = (int*)(smem + 32768);           // 64 KB: [2][8 wv][4 slot][64 lane][4]
    float* redS = (float*)(smem + 32768);         // 32 KB alias of abuf[0] (epilogue only)
    float* denS = (float*)(smem + 32768 + 65536); // 512 B

#define ABUF(bi, slot) (abuf + ((((bi) * 8 + wv) * 4 + (slot)) * 256))

    int t = threadIdx.x, wv = t >> 6, lane = t & 63;
    int m = wv >> 2, p = wv & 3;
    int r = lane & 15, g = lane >> 4;
    int rowbase = blockIdx.x * 32;
    int row = rowbase + m * 16 + r;

    float d = fdst[row];
    const int* arow = adj + (size_t)row * GN + g * 4;   // per-lane base

    // prologue: glds for phase 0 into buffer 0, stage fsL, barrier
    {
        int c0 = p, c1 = p + 4;
        gload_lds16(arow + c0 * 32,      ABUF(0, 0));
        gload_lds16(arow + c0 * 32 + 16, ABUF(0, 1));
        gload_lds16(arow + c1 * 32,      ABUF(0, 2));
        gload_lds16(arow + c1 * 32 + 16, ABUF(0, 3));
        const float4* src = (const float4*)fsrc;
        float4* dst = (float4*)fsL;
#pragma unroll
        for (int i = 0; i < 4; ++i) dst[t + i * 512] = src[t + i * 512];
    }
    __syncthreads();

    f32x4 acc0 = {0.f, 0.f, 0.f, 0.f}, acc1 = acc0, acc2 = acc0, acc3 = acc0;
    float den = 0.f;

    for (int ph = 0; ph < 32; ++ph) {
        int bi = ph & 1;
        int c0 = ph * 8 + p, c1 = c0 + 4;

        // (1) b-fragments for both chunks (L2 hits) — FIRST in the vmem queue
        const uint4* bl0 = whfrag + (size_t)c0 * 256 + lane;
        const uint4* bl1 = whfrag + (size_t)c1 * 256 + lane;
        uint4 b00 = bl0[0], b01 = bl0[64], b02 = bl0[128], b03 = bl0[192];
        uint4 b10 = bl1[0], b11 = bl1[64], b12 = bl1[128], b13 = bl1[192];
        __builtin_amdgcn_sched_barrier(0);

        // (2) DMA next phase's adj into the other buffer
        if (ph + 1 < 32) {
            int nb = bi ^ 1, n0 = c0 + 8, n1 = c1 + 8;
            gload_lds16(arow + n0 * 32,      ABUF(nb, 0));
            gload_lds16(arow + n0 * 32 + 16, ABUF(nb, 1));
            gload_lds16(arow + n1 * 32,      ABUF(nb, 2));
            gload_lds16(arow + n1 * 32 + 16, ABUF(nb, 3));
        }
        __builtin_amdgcn_sched_barrier(0);

        // (3) consume the two staged chunks (data guaranteed by prior barrier)
#pragma unroll
        for (int cl = 0; cl < 2; ++cl) {
            int c = cl ? c1 : c0;
            iv4 alo = *(const iv4*)(ABUF(bi, cl * 2)     + lane * 4);
            iv4 ahi = *(const iv4*)(ABUF(bi, cl * 2 + 1) + lane * 4);
            int ae[8] = {alo[0], alo[1], alo[2], alo[3],
                         ahi[0], ahi[1], ahi[2], ahi[3]};
            float4 s0 = *(const float4*)&fsL[c * 32 + g * 4];
            float4 s1 = *(const float4*)&fsL[c * 32 + 16 + g * 4];
            float se[8] = {s0.x, s0.y, s0.z, s0.w, s1.x, s1.y, s1.z, s1.w};
            bf16x8 af;
            float ws = 0.f;
#pragma unroll
            for (int e = 0; e < 8; ++e) {
                float ev = d + se[e];                   // log2e-scaled
                float lr = fmaxf(ev, 0.2f * ev);        // leakyrelu
                float ex = __builtin_amdgcn_exp2f(lr);  // exp(lrelu(d+s))
                float wvv = (ae[e] > 0) ? ex : 0.f;
                ws += wvv;
                af[e] = (__bf16)wvv;
            }
            den += ws;
            uint4 q0 = cl ? b10 : b00, q1 = cl ? b11 : b01;
            uint4 q2 = cl ? b12 : b02, q3 = cl ? b13 : b03;
            acc0 = __builtin_amdgcn_mfma_f32_16x16x32_bf16(af, __builtin_bit_cast(bf16x8, q0), acc0, 0, 0, 0);
            acc1 = __builtin_amdgcn_mfma_f32_16x16x32_bf16(af, __builtin_bit_cast(bf16x8, q1), acc1, 0, 0, 0);
            acc2 = __builtin_amdgcn_mfma_f32_16x16x32_bf16(af, __builtin_bit_cast(bf16x8, q2), acc2, 0, 0, 0);
            acc3 = __builtin_amdgcn_mfma_f32_16x16x32_bf16(af, __builtin_bit_cast(bf16x8, q3), acc3, 0, 0, 0);
        }
        __syncthreads();   // drains this phase's glds; next phase consumes them
    }

    // epilogue: reduce 4 j-parities. den: cross-g in-wave, cross-p via denS.
    den += __shfl_xor(den, 16);
    den += __shfl_xor(den, 32);
    if (lane < 16) denS[(m * 4 + p) * 16 + lane] = den;
    float* rs = redS + ((size_t)wv * 64 + lane) * 16;
    *(f32x4*)(rs + 0)  = acc0;
    *(f32x4*)(rs + 4)  = acc1;
    *(f32x4*)(rs + 8)  = acc2;
    *(f32x4*)(rs + 12) = acc3;
    __syncthreads();

    // output: thread t -> row or_ = t>>4, cols (t&15)*4 .. +3
    {
        int or_ = t >> 4, c4 = (t & 15) * 4;
        int mm = or_ >> 4, rr = or_ & 15, gg = rr >> 2, reg = rr & 3;
        float dd = denS[(mm * 4 + 0) * 16 + rr] + denS[(mm * 4 + 1) * 16 + rr]
                 + denS[(mm * 4 + 2) * 16 + rr] + denS[(mm * 4 + 3) * 16 + rr];
        float inv = (dd != 0.f) ? 1.f / dd : 0.f;
        float4 o;
        float* op = &o.x;
#pragma unroll
        for (int cc = 0; cc < 4; ++cc) {
            int c = c4 + cc, tq = c >> 4, r2 = c & 15;
            float num = 0.f;
#pragma unroll
            for (int pp = 0; pp < 4; ++pp)
                num += redS[((size_t)(mm * 4 + pp) * 64 + gg * 16 + r2) * 16 + tq * 4 + reg];
            float v = num * inv;
            op[cc] = v > 0.f ? v : __expf(v) - 1.f;     // ELU
        }
        *(float4*)&out[(size_t)(rowbase + or_) * FOUT + c4] = o;
    }
#undef ABUF
}

// ---------------------------------------------------------------------------
extern "C" void kernel_launch(void* const* d_in, const int* in_sizes, int n_in,
                              void* d_out, int out_size, void* d_ws, size_t ws_size,
                              hipStream_t stream) {
    (void)in_sizes; (void)n_in; (void)out_size; (void)ws_size;
    const float* h   = (const float*)d_in[0];
    const int*   adj = (const int*)d_in[1];
    const float* W   = (const float*)d_in[2];
    const float* a   = (const float*)d_in[3];
    float* out = (float*)d_out;

    float* ws     = (float*)d_ws;
    float* fsrc   = ws;                      // 8192 f
    float* fdst   = fsrc + GN;               // 8192 f
    uint4* whfrag = (uint4*)(fdst + GN);     // 65536 uint4 = 1 MB

    k_wh <<<GN / 32, 256, 0, stream>>>(h, W, a, fsrc, fdst, whfrag);
    k_gat<<<GN / 32, 512, 0, stream>>>(adj, fsrc, fdst, whfrag, out);
}

// Round 12
// 125.020 us; speedup vs baseline: 1.0167x; 1.0167x over previous
//
#include <hip/hip_runtime.h>
#include <hip/hip_bf16.h>

#define GN     8192
#define FIN    256
#define FOUT   64
#define NSPLIT 8
#define JSEG   1024      // j columns per split
#define NCH    32        // 32-j chunks per split
#define ROWS_B 128       // rows per k_attn block = 8 waves x 16
#define LOG2E  1.44269504f

typedef float  f32x4  __attribute__((ext_vector_type(4)));
typedef __bf16 bf16x8 __attribute__((ext_vector_type(8)));
typedef int    iv4    __attribute__((ext_vector_type(4)));

__device__ __forceinline__ unsigned short f2bf_rtne(float x) {
    unsigned int u = __float_as_uint(x);
    unsigned int r = (u + 0x7FFFu + ((u >> 16) & 1u)) >> 16;
    return (unsigned short)r;
}

// ---------------------------------------------------------------------------
// K0: adj -> bitmask. Probe-validated load path: plain (non-nontemporal)
// dwordx4, wave reads 1 KB contiguous of one row per instruction, depth-4
// rotation (unroll keeps st[] in registers). Ballot words buffered in LDS,
// flushed as ONE coalesced 1 KB full-wave store per row (r7's divergent 32 B
// stores removed). Word layout per 256-j group gg of row (r7-verified):
//   word[row*256 + gg*8 + h*4 + c] bit p  <->  j = gg*256 + h*128 + p*4 + c
// ---------------------------------------------------------------------------
__global__ __launch_bounds__(256) void k_pack(const int* __restrict__ adj,
                                              unsigned* __restrict__ bmask) {
    __shared__ unsigned lbuf[4][256];
    int wv = threadIdx.x >> 6, lane = threadIdx.x & 63;
    int row = blockIdx.x * 4 + wv;
    const int* rp = adj + (size_t)row * GN;
    iv4 st[4];
#pragma unroll
    for (int dd = 0; dd < 4; ++dd)
        st[dd] = *(const iv4*)(rp + dd * 256 + lane * 4);
#pragma unroll 4
    for (int gg = 0; gg < 32; ++gg) {
        iv4 v = st[gg & 3];
        unsigned long long b0 = __ballot(v[0] > 0);
        unsigned long long b1 = __ballot(v[1] > 0);
        unsigned long long b2 = __ballot(v[2] > 0);
        unsigned long long b3 = __ballot(v[3] > 0);
        int ng = gg + 4;
        if (ng < 32)
            st[gg & 3] = *(const iv4*)(rp + ng * 256 + lane * 4);
        if (lane < 8) {
            unsigned long long s01 = (lane & 1) ? b1 : b0;
            unsigned long long s23 = (lane & 1) ? b3 : b2;
            unsigned long long ss  = (lane & 2) ? s23 : s01;
            lbuf[wv][gg * 8 + lane] = (unsigned)(ss >> ((lane >> 2) * 32));
        }
    }
    // coalesced flush: 64 lanes x 16 B = the row's full 1 KB bitmask
    uint4 o = *(const uint4*)&lbuf[wv][lane * 4];
    *(uint4*)(bmask + (size_t)row * 256 + lane * 4) = o;
}

// ---------------------------------------------------------------------------
// K1: Wh = h @ W (fp32), f_src/f_dst (log2e pre-scaled, clamped), pack 32 Wh
// rows into bf16 MFMA B-fragment layout with within-chunk permutation
// k = gb*8 + e <-> j = gb*4 + (e&3) + 16*(e>>2).  (unchanged, verified)
// ---------------------------------------------------------------------------
__global__ __launch_bounds__(256) void k_wh(const float* __restrict__ h,
                                            const float* __restrict__ W,
                                            const float* __restrict__ a,
                                            float* __restrict__ fsrc,
                                            float* __restrict__ fdst,
                                            uint4* __restrict__ whfrag) {
    __shared__ float Wt[FOUT][FIN + 1];
    __shared__ float WhL[32][FOUT + 1];
    int t = threadIdx.x;
    int col = t & 63, kq4 = t >> 6;
#pragma unroll
    for (int rep = 0; rep < 16; ++rep) {
        int k0 = kq4 * 4 + rep * 16;
        float4 wv;
        wv.x = W[(k0 + 0) * FOUT + col];
        wv.y = W[(k0 + 1) * FOUT + col];
        wv.z = W[(k0 + 2) * FOUT + col];
        wv.w = W[(k0 + 3) * FOUT + col];
        *(float4*)&Wt[col][k0] = wv;
    }
    __syncthreads();
    int wave = t >> 6, lane = t & 63;
    float a1 = a[lane], a2 = a[FOUT + lane];
    int bid = blockIdx.x;
#pragma unroll
    for (int rr = 0; rr < 8; ++rr) {
        int il = wave * 8 + rr;
        int i  = bid * 32 + il;
        const float* hrow = h + (size_t)i * FIN;
        float acc = 0.f;
#pragma unroll 8
        for (int k0 = 0; k0 < FIN; k0 += 4) {
            float4 hv = *(const float4*)&hrow[k0];
            float4 wv = *(const float4*)&Wt[lane][k0];
            acc += hv.x * wv.x + hv.y * wv.y + hv.z * wv.z + hv.w * wv.w;
        }
        WhL[il][lane] = acc;
        float v1 = acc * a1, v2 = acc * a2;
#pragma unroll
        for (int off = 32; off > 0; off >>= 1) {
            v1 += __shfl_xor(v1, off);
            v2 += __shfl_xor(v2, off);
        }
        if (lane == 0) {
            fsrc[i] = fminf(v1, 30.f) * LOG2E;
            fdst[i] = fminf(v2, 30.f) * LOG2E;
        }
    }
    __syncthreads();
    int lane2 = t & 63, ct = t >> 6;
    int colc = ct * 16 + (lane2 & 15);
    int gb = lane2 >> 4;
    unsigned int pk[4];
#pragma unroll
    for (int p = 0; p < 4; ++p) {
        int jo = ((p >> 1) * 16) + gb * 4 + (p & 1) * 2;
        unsigned int lo = f2bf_rtne(WhL[jo    ][colc]);
        unsigned int hi = f2bf_rtne(WhL[jo + 1][colc]);
        pk[p] = lo | (hi << 16);
    }
    uint4 o; o.x = pk[0]; o.y = pk[1]; o.z = pk[2]; o.w = pk[3];
    whfrag[(size_t)(bid * 4 + ct) * 64 + lane2] = o;
}

// ---------------------------------------------------------------------------
// K2: attention + PV from the bitmask (r7-verified consumer). Block = 128
// rows x 1024-j split, 8 waves x 16 rows. Lane preloads its row's 1024-j bit
// slice (8 uint4, statically indexed under full unroll); main loop has no
// VMEM, no barriers. __launch_bounds__(512, 1): the r7 (512,2) variant
// capped VGPRs at 128 and spilled the ~130-reg working set to scratch inside
// the inner loop — suspected cause of its ~60 us runtime.
// ---------------------------------------------------------------------------
__global__ __launch_bounds__(512, 1) void k_attn(const unsigned* __restrict__ bmask,
                                                 const float* __restrict__ fsrc,
                                                 const float* __restrict__ fdst,
                                                 const uint4* __restrict__ whfrag,
                                                 float* __restrict__ pacc,
                                                 float* __restrict__ pden) {
    __shared__ uint4 whL[NCH * 4 * 64];   // 128 KB
    __shared__ float fsL[JSEG];           // 4 KB

    int t = threadIdx.x, wv = t >> 6, lane = t & 63;
    int bid = blockIdx.x;
    int rt = bid >> 3, q = bid & (NSPLIT - 1);
    int rowbase = rt * ROWS_B;
    int r = lane & 15, g = lane >> 4;
    int row = rowbase + wv * 16 + r;

    // preload bit slice + d (VMEM latency overlaps LDS staging below)
    const uint4* bm4 = (const uint4*)bmask + (size_t)row * 64 + q * 8;
    uint4 M[8];
#pragma unroll
    for (int i = 0; i < 8; ++i) M[i] = bm4[i];
    float d = fdst[row];

    {
        const uint4* src = whfrag + (size_t)q * (NCH * 4 * 64);
#pragma unroll
        for (int it = 0; it < 16; ++it) whL[it * 512 + t] = src[it * 512 + t];
        if (t < 256) *(float4*)&fsL[t * 4] = *(const float4*)&fsrc[q * JSEG + t * 4];
    }
    __syncthreads();

    f32x4 acc0 = {0.f, 0.f, 0.f, 0.f}, acc1 = acc0, acc2 = acc0, acc3 = acc0;
    float den = 0.f;

#pragma unroll
    for (int grp = 0; grp < 4; ++grp) {
#pragma unroll
        for (int chl = 0; chl < 8; ++chl) {
            int ch = grp * 8 + chl;
            uint4 W4 = M[grp * 2 + (chl >> 2)];            // static index
            float4 s0 = *(const float4*)&fsL[ch * 32 + g * 4];
            float4 s1 = *(const float4*)&fsL[ch * 32 + 16 + g * 4];
            const uint4* bl = &whL[(ch * 4) * 64 + lane];
            uint4 b0 = bl[0], b1 = bl[64], b2 = bl[128], b3 = bl[192];
            unsigned wc[4] = {W4.x, W4.y, W4.z, W4.w};
            float se[8] = {s0.x, s0.y, s0.z, s0.w, s1.x, s1.y, s1.z, s1.w};
            int sb = (chl & 3) * 8 + g;
            bf16x8 af;
            float ws = 0.f;
#pragma unroll
            for (int e = 0; e < 8; ++e) {
                float ev = d + se[e];                       // log2e-scaled
                float lr = fmaxf(ev, 0.2f * ev);            // leakyrelu
                float ex = __builtin_amdgcn_exp2f(lr);      // exp(lrelu(d+s))
                unsigned bit = (wc[e & 3] >> (sb + (e >> 2) * 4)) & 1u;
                float wvv = bit ? ex : 0.f;
                ws += wvv;
                af[e] = (__bf16)wvv;
            }
            den += ws;
            acc0 = __builtin_amdgcn_mfma_f32_16x16x32_bf16(af, __builtin_bit_cast(bf16x8, b0), acc0, 0, 0, 0);
            acc1 = __builtin_amdgcn_mfma_f32_16x16x32_bf16(af, __builtin_bit_cast(bf16x8, b1), acc1, 0, 0, 0);
            acc2 = __builtin_amdgcn_mfma_f32_16x16x32_bf16(af, __builtin_bit_cast(bf16x8, b2), acc2, 0, 0, 0);
            acc3 = __builtin_amdgcn_mfma_f32_16x16x32_bf16(af, __builtin_bit_cast(bf16x8, b3), acc3, 0, 0, 0);
        }
    }

    den += __shfl_xor(den, 16);
    den += __shfl_xor(den, 32);

    float* po = pacc + (size_t)q * (GN * FOUT);
    int orow = rowbase + wv * 16 + g * 4;
#pragma unroll
    for (int reg = 0; reg < 4; ++reg) {
        po[(size_t)(orow + reg) * FOUT +  0 + r] = acc0[reg];
        po[(size_t)(orow + reg) * FOUT + 16 + r] = acc1[reg];
        po[(size_t)(orow + reg) * FOUT + 32 + r] = acc2[reg];
        po[(size_t)(orow + reg) * FOUT + 48 + r] = acc3[reg];
    }
    if (g == 0) pden[(size_t)q * GN + row] = den;
}

// ---------------------------------------------------------------------------
// K3: combine partials, divide by denominator, ELU. (verified, unchanged)
// ---------------------------------------------------------------------------
__global__ __launch_bounds__(256) void k_out(const float* __restrict__ pacc,
                                             const float* __restrict__ pden,
                                             float* __restrict__ out) {
    int idx = blockIdx.x * 256 + threadIdx.x;
    int i = idx >> 6;
    float num = 0.f, den = 0.f;
#pragma unroll
    for (int qq = 0; qq < NSPLIT; ++qq) {
        num += pacc[(size_t)qq * (GN * FOUT) + idx];
        den += pden[(size_t)qq * GN + i];
    }
    float v = (den != 0.f) ? num / den : 0.f;
    out[idx] = v > 0.f ? v : __expf(v) - 1.f;
}

// ---------------------------------------------------------------------------
extern "C" void kernel_launch(void* const* d_in, const int* in_sizes, int n_in,
                              void* d_out, int out_size, void* d_ws, size_t ws_size,
                              hipStream_t stream) {
    (void)in_sizes; (void)n_in; (void)out_size; (void)ws_size;
    const float* h   = (const float*)d_in[0];
    const int*   adj = (const int*)d_in[1];
    const float* W   = (const float*)d_in[2];
    const float* a   = (const float*)d_in[3];
    float* out = (float*)d_out;

    float* ws       = (float*)d_ws;
    float* fsrc     = ws;                                    // 8192 f
    float* fdst     = fsrc + GN;                             // 8192 f
    uint4* whfrag   = (uint4*)(fdst + GN);                   // 65536 uint4 = 1 MB
    float* pacc     = (float*)(whfrag + (size_t)GN / 32 * 4 * 64);
    float* pden     = pacc + (size_t)NSPLIT * GN * FOUT;     // NSPLIT*8192 f
    unsigned* bmask = (unsigned*)(pden + (size_t)NSPLIT * GN); // 2M words = 8 MB

    k_pack<<<GN / 4,                  256, 0, stream>>>(adj, bmask);
    k_wh  <<<GN / 32,                 256, 0, stream>>>(h, W, a, fsrc, fdst, whfrag);
    k_attn<<<(GN / ROWS_B) * NSPLIT,  512, 0, stream>>>(bmask, fsrc, fdst, whfrag, pacc, pden);
    k_out <<<GN * FOUT / 256,         256, 0, stream>>>(pacc, pden, out);
}